// Round 17
// baseline (275.194 us; speedup 1.0000x reference)
//
#include <hip/hip_runtime.h>
#include <cmath>
#include <cfloat>

#define NUM_EMB 1024
#define EMB_DIM 256
#define BATCH 32
#define SEQ 2048
#define NROWS 65536            // BATCH*SEQ
// d_out offsets (floats): [loss | quantized (b,c,l) | perplexity | encodings (N,K)]
#define Q_OFF 1
#define PERP_OFF 16777217
#define ENC_OFF 16777218
// ws offsets (bytes)
#define WS_IDX 0
#define WS_E2     (NROWS * 4)
#define WS_COUNTS (WS_E2 + NUM_EMB * 4)
#define WS_SSE    (WS_COUNTS + NUM_EMB * 4)
#define WS_EMX    (WS_SSE + 1024 * 8)

typedef __attribute__((ext_vector_type(8))) short short8v;
typedef __attribute__((ext_vector_type(16))) float f32x16;
#define MFMA(a,b,c) __builtin_amdgcn_mfma_f32_32x32x16_bf16(a,b,c,0,0,0)

// square with a barrier so the compiler cannot contract x*x into a following add
__device__ __forceinline__ float sqg(float x) {
    float s = x * x;
    asm volatile("" : "+v"(s));
    return s;
}

// RNE float->bf16
__device__ __forceinline__ unsigned short f2bf(float f) {
    unsigned u = __float_as_uint(f);
    unsigned r = u + 0x7FFFu + ((u >> 16) & 1u);
    return (unsigned short)(r >> 16);
}

// order-preserving float<->uint maps
__device__ __forceinline__ unsigned f2ord(float f) {
    unsigned u = __float_as_uint(f);
    return (u & 0x80000000u) ? ~u : (u | 0x80000000u);
}
__device__ __forceinline__ float ord2f(unsigned o) {
    unsigned u = (o & 0x80000000u) ? (o & 0x7FFFFFFFu) : ~o;
    return __uint_as_float(u);
}

// numpy pairwise sum of squares over 256 elements (AVX512 path replica)
template <int STRIDE>
__device__ float np_sumsq256(const float* __restrict__ p) {
    float total = 0.0f;
#pragma unroll
    for (int h = 0; h < 2; ++h) {
        const int base = 128 * h;
        float c[16];
#pragma unroll
        for (int l = 0; l < 16; ++l) {
            float t0 = sqg(p[(size_t)(base + l) * STRIDE]);
            float t1 = sqg(p[(size_t)(base + 16 + l) * STRIDE]);
            float t2 = sqg(p[(size_t)(base + 32 + l) * STRIDE]);
            float t3 = sqg(p[(size_t)(base + 48 + l) * STRIDE]);
            float t4 = sqg(p[(size_t)(base + 64 + l) * STRIDE]);
            float t5 = sqg(p[(size_t)(base + 80 + l) * STRIDE]);
            float t6 = sqg(p[(size_t)(base + 96 + l) * STRIDE]);
            float t7 = sqg(p[(size_t)(base + 112 + l) * STRIDE]);
            c[l] = ((t0 + t1) + (t2 + t3)) + ((t4 + t5) + (t6 + t7));
        }
        float u[8];
#pragma unroll
        for (int l = 0; l < 8; ++l) u[l] = c[l] + c[l + 8];
        float v[4];
#pragma unroll
        for (int l = 0; l < 4; ++l) v[l] = u[l] + u[l + 4];
        float w0 = v[0] + v[2];
        float w1 = v[1] + v[3];
        float hh = w0 + w1;
        total = (h == 0) ? hh : (total + hh);
    }
    return total;
}

// Fused setup: blocks 0-3 = e2 + counts-zero + per-block emb-norm max (plain store);
// blocks 4-35 = bf16 E image prep.  ebf[p][c] = 16B = e[c][8p..8p+7] bf16.
__global__ __launch_bounds__(256) void k_setup(const float* __restrict__ emb,
                                               float* __restrict__ e2,
                                               float* __restrict__ emax4,
                                               int* __restrict__ counts,
                                               char* __restrict__ ebf) {
    const int bid = blockIdx.x;
    const int tid = threadIdx.x;
    if (bid < 4) {
        const int k = bid * 256 + tid;
        float v = np_sumsq256<1>(emb + (size_t)k * EMB_DIM);
        e2[k] = v;
        counts[k] = 0;
        __shared__ float red[256];
        red[tid] = sqrtf(v);
        __syncthreads();
        for (int s = 128; s > 0; s >>= 1) {
            if (tid < s) red[tid] = fmaxf(red[tid], red[tid + s]);
            __syncthreads();
        }
        if (tid == 0) emax4[bid] = red[0];
    } else {
        const int t = (bid - 4) * 256 + tid;   // 8192 threads
        const int c = t & 1023;
        const int s = t >> 10;                 // 0..7
#pragma unroll
        for (int g = 0; g < 4; ++g) {
            const int p = s + 8 * g;
            const float* e = emb + (size_t)c * EMB_DIM + 8 * p;
            unsigned h[8];
#pragma unroll
            for (int j = 0; j < 8; ++j) h[j] = f2bf(e[j]);
            uint4 w;
            w.x = h[0] | (h[1] << 16);
            w.y = h[2] | (h[3] << 16);
            w.z = h[4] | (h[5] << 16);
            w.w = h[6] | (h[7] << 16);
            *(uint4*)(ebf + ((size_t)p << 14) + ((size_t)c << 4)) = w;
        }
    }
}

// Fused distance+argmin+quantize+ENCODINGS. 1024 blocks x 256 thr (4 waves),
// 4 blocks/CU. R17: each block writes its own 64 one-hot enc rows (256 KB) right
// after rescore — overlapping the write wall with the latency-bound interior.
// Blocks < 35 defer (their enc rows are the ebf/rowListG scratch still being
// read by other blocks); k_fix rewrites rows 0..2239 afterwards.
__global__ __launch_bounds__(256, 4) void k_dist(
    const float* __restrict__ in, const char* __restrict__ ebf,
    const float* __restrict__ emb, const float* __restrict__ e2g,
    const float* __restrict__ emax4,
    int* __restrict__ idx, int* __restrict__ counts,
    float* __restrict__ qout, double* __restrict__ ssep,
    int2* __restrict__ rowListG, float* __restrict__ enc)
{
    __shared__ __align__(16) char pool[32768];  // X tile; xlds|queue|rowBest; then T|rd
    __shared__ float e2s[1024];
    __shared__ float vpart[64][8];
    __shared__ float A_lds[64];
    __shared__ float wRow[64];
    __shared__ unsigned rowMinU[64];
    __shared__ int rowCnt[64];
    __shared__ int rrows[64];
    __shared__ int rslot[64];
    __shared__ int qn, nrr;

    const int tid = threadIdx.x;
    const int n0 = blockIdx.x << 6;
    const int b = n0 >> 11;
    const int l0 = n0 & 2047;
    const int lane = tid & 63;
    const int wv = tid >> 6;
    const int lm = lane & 31;
    const int lh = lane >> 5;
    int2* rlist = rowListG + ((size_t)blockIdx.x << 10);   // 64 rows x 16 slots

    if (tid < 64) { rowMinU[tid] = 0xFFFFFFFFu; rowCnt[tid] = 0; }
    if (tid == 0) { qn = 0; nrr = 0; }
    ((float4*)e2s)[tid] = ((const float4*)e2g)[tid];   // 1024 floats

    // ---- stage X (bf16, 16-slot XOR swizzle) + exact numpy-pairwise rowsum ----
    // float2 along l: thread (o, hh, rp) owns d-class o of 128-half hh for rows
    // 2rp, 2rp+1. Same squares, same per-row tree, same single-writer per (r,d).
    {
        const int o  = tid >> 6;          // d residue class (mod 4)
        const int hh = (tid >> 5) & 1;    // which 128-half of d
        const int rp = tid & 31;          // row pair: rows 2rp, 2rp+1
        const int r0 = 2 * rp;
        const int r1 = r0 + 1;
        const float* xcol = in + (size_t)b * 524288 + l0 + r0;
        float ta[32], tb[32];
#pragma unroll
        for (int it = 0; it < 32; ++it) {
            const int d = 128 * hh + 4 * it + o;
            const float2 v2 = *(const float2*)(xcol + (size_t)d * 2048);
            *(unsigned short*)(pool + r0 * 512 + ((2 * d) ^ ((r0 & 15) << 4))) = f2bf(v2.x);
            *(unsigned short*)(pool + r1 * 512 + ((2 * d) ^ ((r1 & 15) << 4))) = f2bf(v2.y);
            ta[it] = sqg(v2.x);
            tb[it] = sqg(v2.y);
        }
        float cja[4], cjb[4];
#pragma unroll
        for (int j = 0; j < 4; ++j) {
            cja[j] = ((ta[j] + ta[4 + j]) + (ta[8 + j] + ta[12 + j]))
                   + ((ta[16 + j] + ta[20 + j]) + (ta[24 + j] + ta[28 + j]));
            cjb[j] = ((tb[j] + tb[4 + j]) + (tb[8 + j] + tb[12 + j]))
                   + ((tb[16 + j] + tb[20 + j]) + (tb[24 + j] + tb[28 + j]));
        }
        vpart[r0][hh * 4 + o] = (cja[0] + cja[2]) + (cja[1] + cja[3]);
        vpart[r1][hh * 4 + o] = (cjb[0] + cjb[2]) + (cjb[1] + cjb[3]);
    }
    __syncthreads();
    const float EMX = fmaxf(fmaxf(emax4[0], emax4[1]), fmaxf(emax4[2], emax4[3]));
    if (tid < 64) {
        const float* vp = vpart[tid];
        float h0 = (vp[0] + vp[2]) + (vp[1] + vp[3]);
        float h1 = (vp[4] + vp[6]) + (vp[5] + vp[7]);
        float A = h0 + h1;
        A_lds[tid] = A;
        // rigorous: 2*E_mfma + rounding slop = 2^-7 * ||x|| * max||e|| + 1e-4
        wRow[tid] = 0.0078125f * sqrtf(A) * EMX + 1.0e-4f;
    }
    __syncthreads();

    const int rsw = (lm & 15) << 4;     // same for rows lm and lm+32
    const int rb0 = lm * 512;
    const int rb1 = (32 + lm) * 512;
    const float wr0 = wRow[lm];
    const float wr1 = wRow[32 + lm];

    for (int pass = 0; pass < 4; ++pass) {
        const int cbase = pass * 256 + wv * 64;
        const int c0 = cbase + lm;      // eA input codes (A-frag row = lane&31)
        const int c1 = c0 + 32;         // eB

        f32x16 acc00, acc01, acc10, acc11;   // [e-frag][x-frag]
#pragma unroll
        for (int i = 0; i < 16; ++i) { acc00[i] = 0.f; acc01[i] = 0.f; acc10[i] = 0.f; acc11[i] = 0.f; }

        // 1-deep pipeline (4-deep measured null in R10; keep simplest form)
        const char* bp0 = ebf + ((size_t)lh << 14);
        short8v eAc = *(const short8v*)(bp0 + ((size_t)c0 << 4));
        short8v eBc = *(const short8v*)(bp0 + ((size_t)c1 << 4));
        for (int ks = 0; ks < 16; ++ks) {
            short8v eAn, eBn;
            if (ks < 15) {
                const char* bp = ebf + ((size_t)(2 * ks + 2 + lh) << 14);
                eAn = *(const short8v*)(bp + ((size_t)c0 << 4));
                eBn = *(const short8v*)(bp + ((size_t)c1 << 4));
            }
            const int koff = 32 * ks + 16 * lh;
            short8v x0 = *(const short8v*)(pool + rb0 + (koff ^ rsw));
            short8v x1 = *(const short8v*)(pool + rb1 + (koff ^ rsw));
            acc00 = MFMA(eAc, x0, acc00);
            acc01 = MFMA(eAc, x1, acc01);
            acc10 = MFMA(eBc, x0, acc10);
            acc11 = MFMA(eBc, x1, acc11);
            if (ks < 15) { eAc = eAn; eBc = eBn; }
        }

        // scores in place: s = e2[code] - 2*dot; per-row min purely in-register
        float rm0 = FLT_MAX, rm1 = FLT_MAX;
#pragma unroll
        for (int i = 0; i < 16; ++i) {
            const int crow = (i & 3) + 8 * (i >> 2) + 4 * lh;
            const float ezA = e2s[cbase + crow];
            const float ezB = e2s[cbase + 32 + crow];
            acc00[i] = __builtin_fmaf(-2.f, acc00[i], ezA);
            acc10[i] = __builtin_fmaf(-2.f, acc10[i], ezB);
            acc01[i] = __builtin_fmaf(-2.f, acc01[i], ezA);
            acc11[i] = __builtin_fmaf(-2.f, acc11[i], ezB);
            rm0 = fminf(rm0, fminf(acc00[i], acc10[i]));
            rm1 = fminf(rm1, fminf(acc01[i], acc11[i]));
        }
        atomicMin(&rowMinU[lm], f2ord(rm0));
        atomicMin(&rowMinU[32 + lm], f2ord(rm1));
        __syncthreads();   // tight thresholds: all waves' minima for passes <= pass

        const float thr0 = ord2f(rowMinU[lm]) + wr0;
        const float thr1 = ord2f(rowMinU[32 + lm]) + wr1;
#pragma unroll
        for (int i = 0; i < 16; ++i) {
            const int crow = (i & 3) + 8 * (i >> 2) + 4 * lh;
            const int ccA = cbase + crow;
            const int ccB = ccA + 32;
            if (acc00[i] <= thr0) { int p = atomicAdd(&rowCnt[lm], 1);      if (p < 16) rlist[lm * 16 + p]        = make_int2(ccA, __float_as_int(acc00[i])); }
            if (acc10[i] <= thr0) { int p = atomicAdd(&rowCnt[lm], 1);      if (p < 16) rlist[lm * 16 + p]        = make_int2(ccB, __float_as_int(acc10[i])); }
            if (acc01[i] <= thr1) { int p = atomicAdd(&rowCnt[32 + lm], 1); if (p < 16) rlist[(32 + lm) * 16 + p] = make_int2(ccA, __float_as_int(acc01[i])); }
            if (acc11[i] <= thr1) { int p = atomicAdd(&rowCnt[32 + lm], 1); if (p < 16) rlist[(32 + lm) * 16 + p] = make_int2(ccB, __float_as_int(acc11[i])); }
        }
    }
    __syncthreads();

    // ---- X tile dead: overlay xlds (16 rows fp32) | queue | rowBest in pool ----
    float* xlds = (float*)pool;                                        // 16 KB
    int2* queue = (int2*)(pool + 16384);                               // 8 KB (max 1024)
    unsigned long long* rowBest = (unsigned long long*)(pool + 24576); // 512 B

    int myBest = -1;
    if (tid < 64) {
        const int rr = tid;
        const int myCnt = rowCnt[rr];
        rowBest[rr] = ~0ull;
        rslot[rr] = -1;
        bool need = false;
        if (myCnt > 16) {
            need = true;   // overflow: exact full scan from LDS rows below
        } else {
            const float thr = ord2f(rowMinU[rr]) + wRow[rr];
            int myNv = 0, lk = -1;
            for (int s = 0; s < myCnt; ++s) {
                int2 en = rlist[rr * 16 + s];
                if (__int_as_float(en.y) <= thr) { ++myNv; lk = en.x; }
            }
            if (myNv == 1) {
                myBest = lk;
            } else {
                need = true;
                for (int s = 0; s < myCnt; ++s) {
                    int2 en = rlist[rr * 16 + s];
                    if (__int_as_float(en.y) <= thr) {
                        int p = atomicAdd(&qn, 1);
                        queue[p] = make_int2(rr, en.x);
                    }
                }
            }
        }
        if (need) { int s = atomicAdd(&nrr, 1); rrows[s] = rr; rslot[rr] = s; }
    }
    __syncthreads();

    const int QN = qn;
    const int NR = nrr;
    for (int chunk = 0; chunk < NR; chunk += 16) {
        const int cn = (NR - chunk < 16) ? (NR - chunk) : 16;
        // cooperative fp32 row copy (bit-exact; L2-hot from staging)
        for (int i = tid; i < cn * 256; i += 256) {
            const int s = i >> 8;
            const int d = i & 255;
            const int rr = rrows[chunk + s];
            xlds[s * 256 + d] = in[(size_t)b * 524288 + (size_t)d * 2048 + (l0 + rr)];
        }
        __syncthreads();
        // queue rescore for rows in this chunk: exact ascending-d fmaf chain, x from LDS
        for (int e = tid; e < QN; e += 256) {
            const int2 en = queue[e];
            const int rr = en.x;
            const int sl = rslot[rr] - chunk;
            if (sl < 0 || sl >= cn) continue;
            const int k = en.y;
            const float* xr = xlds + sl * 256;
            const float* er = emb + (size_t)k * EMB_DIM;
            float acc2 = 0.0f;
            for (int d = 0; d < 256; d += 4) {
                const float4 ev = *(const float4*)(er + d);
                const float4 xv = *(const float4*)(xr + d);
                acc2 = __builtin_fmaf(xv.x, ev.x, acc2);
                acc2 = __builtin_fmaf(xv.y, ev.y, acc2);
                acc2 = __builtin_fmaf(xv.z, ev.z, acc2);
                acc2 = __builtin_fmaf(xv.w, ev.w, acc2);
            }
            const float t = A_lds[rr] + e2s[k];
            const float dist = t - 2.0f * acc2;
            const unsigned long long pk = ((unsigned long long)f2ord(dist) << 32) | (unsigned)k;
            atomicMin(&rowBest[rr], pk);
        }
        // overflow rows in this chunk: all 1024 codes, 4 per thread, x from LDS
        for (int i = tid; i < cn * 256; i += 256) {
            const int s = i >> 8;
            const int rr = rrows[chunk + s];
            if (rowCnt[rr] <= 16) continue;
            const int kb = i & 255;
            const float* xr = xlds + s * 256;
            const float A = A_lds[rr];
            for (int k = kb; k < NUM_EMB; k += 256) {
                const float* er = emb + (size_t)k * EMB_DIM;
                float acc2 = 0.0f;
                for (int d = 0; d < 256; d += 4) {
                    const float4 ev = *(const float4*)(er + d);
                    const float4 xv = *(const float4*)(xr + d);
                    acc2 = __builtin_fmaf(xv.x, ev.x, acc2);
                    acc2 = __builtin_fmaf(xv.y, ev.y, acc2);
                    acc2 = __builtin_fmaf(xv.z, ev.z, acc2);
                    acc2 = __builtin_fmaf(xv.w, ev.w, acc2);
                }
                const float t = A + e2s[k];
                const float dist = t - 2.0f * acc2;
                const unsigned long long pk = ((unsigned long long)f2ord(dist) << 32) | (unsigned)k;
                atomicMin(&rowBest[rr], pk);
            }
        }
        __syncthreads();   // protect xlds before next chunk's copy
    }

    if (tid < 64) {
        int bk = myBest;
        if (bk < 0) bk = (int)(rowBest[tid] & 0xFFFFFFFFull);
        idx[n0 + tid] = bk;
        atomicAdd(&counts[bk], 1);
        rowCnt[tid] = bk;   // reuse as on-chip lidx for the enc + quant tails
    }
    __syncthreads();

    // ---- fused one-hot enc writes (own 64 rows, 256 KB), blocks >= 35 only ----
    // (rows 0..2239 overlap the ebf/rowListG scratch other blocks still read;
    //  k_fix rewrites them after k_dist completes)
    if (blockIdx.x >= 35) {
        float* encb = enc + ((size_t)n0 << 10);
        const int kk = tid << 2;
#pragma unroll 4
        for (int it = 0; it < 64; ++it) {
            const int e = rowCnt[it];   // broadcast LDS read
            float4 v;
            v.x = (e == kk) ? 1.0f : 0.0f;
            v.y = (e == kk + 1) ? 1.0f : 0.0f;
            v.z = (e == kk + 2) ? 1.0f : 0.0f;
            v.w = (e == kk + 3) ? 1.0f : 0.0f;
            *(float4*)(encb + (size_t)it * 1024 + kk) = v;
        }
    }

    // ---- fused quantize tail (was k_quant): rows (b, l0..l0+63), all 256 c ----
    // pool is dead again: T[64][65] fp32 (16.6 KB) + rd double[256] (2 KB).
    float* T = (float*)pool;
    double* rd = (double*)(pool + 20480);
    double sse = 0.0;
    for (int ch = 0; ch < 4; ++ch) {
        // load: T[lo][cl] = emb[lidx[lo]][ch*64+cl]; lanes vary cl -> coalesced 256B
        for (int g = 0; g < 16; ++g) {
            const int lo = g * 4 + (tid >> 6);
            const int cl = tid & 63;
            T[lo * 65 + cl] = emb[(size_t)rowCnt[lo] * EMB_DIM + ch * 64 + cl];
        }
        __syncthreads();
        // write + SSE: lanes vary lo -> coalesced 256B stores; T read stride 65 (conflict-free)
        for (int g = 0; g < 16; ++g) {
            const int cl = g * 4 + (tid >> 6);
            const int lo = tid & 63;
            const float q = T[lo * 65 + cl];
            const size_t ga = (size_t)b * 524288 + (size_t)(ch * 64 + cl) * 2048 + l0 + lo;
            const float x = in[ga];
            qout[ga] = q;
            const float d = q - x;
            sse += (double)d * (double)d;
        }
        __syncthreads();   // protect T before next chunk's load
    }
    rd[tid] = sse;
    __syncthreads();
    for (int st = 128; st > 0; st >>= 1) {
        if (tid < st) rd[tid] += rd[tid + st];
        __syncthreads();
    }
    if (tid == 0) ssep[blockIdx.x] = rd[0];
}

// Fixup + final: blocks 0..34 rewrite enc rows 0..2239 (the scratch-overlapped
// region k_dist deferred); block 35 does the loss/perplexity reduction.
__global__ __launch_bounds__(256) void k_fix(const int* __restrict__ idx,
                                             float* __restrict__ enc,
                                             const double* __restrict__ ssep,
                                             const int* __restrict__ counts,
                                             float* __restrict__ out)
{
    const int bid = blockIdx.x;
    const int tid = threadIdx.x;
    if (bid < 35) {
        const int n0 = bid << 6;
        const int kk = tid << 2;
        float* encb = enc + ((size_t)n0 << 10);
#pragma unroll 4
        for (int it = 0; it < 64; ++it) {
            const int e = idx[n0 + it];
            float4 v;
            v.x = (e == kk) ? 1.0f : 0.0f;
            v.y = (e == kk + 1) ? 1.0f : 0.0f;
            v.z = (e == kk + 2) ? 1.0f : 0.0f;
            v.w = (e == kk + 3) ? 1.0f : 0.0f;
            *(float4*)(encb + (size_t)it * 1024 + kk) = v;
        }
        return;
    }
    __shared__ double rd[256];
    double s = 0.0;
    for (int i = tid; i < 1024; i += 256) s += ssep[i];
    rd[tid] = s;
    __syncthreads();
    for (int st = 128; st > 0; st >>= 1) {
        if (tid < st) rd[tid] += rd[tid + st];
        __syncthreads();
    }
    const double total = rd[0];
    __syncthreads();
    double pl = 0.0;
    for (int k = tid; k < 1024; k += 256) {
        const double p = (double)counts[k] * (1.0 / 65536.0);
        pl += p * log(p + 1e-10);
    }
    rd[tid] = pl;
    __syncthreads();
    for (int st = 128; st > 0; st >>= 1) {
        if (tid < st) rd[tid] += rd[tid + st];
        __syncthreads();
    }
    if (tid == 0) {
        out[0] = (float)(1.25 * (total * (1.0 / 16777216.0)));
        out[PERP_OFF] = (float)exp(-rd[0]);
    }
}

extern "C" void kernel_launch(void* const* d_in, const int* in_sizes, int n_in,
                              void* d_out, int out_size, void* d_ws, size_t ws_size,
                              hipStream_t stream)
{
    const float* in  = (const float*)d_in[0];
    const float* emb = (const float*)d_in[1];
    float* out = (float*)d_out;
    char* ws = (char*)d_ws;
    int*     idx    = (int*)(ws + WS_IDX);
    float*   e2     = (float*)(ws + WS_E2);
    int*     counts = (int*)(ws + WS_COUNTS);
    double*  ssep   = (double*)(ws + WS_SSE);
    float*   emax4  = (float*)(ws + WS_EMX);

    // scratch carved from the encodings output region (rows 0..2239, rewritten
    // by k_fix): [ebf: 512 KB bf16 E image][rowListG: 8 MB candidate lists]
    float* enc = out + ENC_OFF;
    char* ebf = (char*)enc + 8;              // 16B-aligned
    int2* rowListG = (int2*)(ebf + (512 << 10));

    k_setup<<<dim3(36), dim3(256), 0, stream>>>(emb, e2, emax4, counts, ebf);
    k_dist<<<dim3(1024), dim3(256), 0, stream>>>(in, ebf, emb, e2, emax4, idx, counts,
                                                 out + Q_OFF, ssep, rowListG, enc);
    k_fix<<<dim3(36), dim3(256), 0, stream>>>(idx, enc, ssep, counts, out);
}

// Round 18
// 232.633 us; speedup vs baseline: 1.1830x; 1.1830x over previous
//
#include <hip/hip_runtime.h>
#include <cmath>
#include <cfloat>

#define NUM_EMB 1024
#define EMB_DIM 256
#define BATCH 32
#define SEQ 2048
#define NROWS 65536            // BATCH*SEQ
// d_out offsets (floats): [loss | quantized (b,c,l) | perplexity | encodings (N,K)]
#define Q_OFF 1
#define PERP_OFF 16777217
#define ENC_OFF 16777218
// ws offsets (bytes)
#define WS_IDX 0
#define WS_E2     (NROWS * 4)
#define WS_COUNTS (WS_E2 + NUM_EMB * 4)
#define WS_SSE    (WS_COUNTS + NUM_EMB * 4)
#define WS_EMX    (WS_SSE + 1024 * 8)

typedef __attribute__((ext_vector_type(8))) short short8v;
typedef __attribute__((ext_vector_type(16))) float f32x16;
#define MFMA(a,b,c) __builtin_amdgcn_mfma_f32_32x32x16_bf16(a,b,c,0,0,0)

// square with a barrier so the compiler cannot contract x*x into a following add
__device__ __forceinline__ float sqg(float x) {
    float s = x * x;
    asm volatile("" : "+v"(s));
    return s;
}

// RNE float->bf16
__device__ __forceinline__ unsigned short f2bf(float f) {
    unsigned u = __float_as_uint(f);
    unsigned r = u + 0x7FFFu + ((u >> 16) & 1u);
    return (unsigned short)(r >> 16);
}

// order-preserving float<->uint maps
__device__ __forceinline__ unsigned f2ord(float f) {
    unsigned u = __float_as_uint(f);
    return (u & 0x80000000u) ? ~u : (u | 0x80000000u);
}
__device__ __forceinline__ float ord2f(unsigned o) {
    unsigned u = (o & 0x80000000u) ? (o & 0x7FFFFFFFu) : ~o;
    return __uint_as_float(u);
}

// numpy pairwise sum of squares over 256 elements (AVX512 path replica)
template <int STRIDE>
__device__ float np_sumsq256(const float* __restrict__ p) {
    float total = 0.0f;
#pragma unroll
    for (int h = 0; h < 2; ++h) {
        const int base = 128 * h;
        float c[16];
#pragma unroll
        for (int l = 0; l < 16; ++l) {
            float t0 = sqg(p[(size_t)(base + l) * STRIDE]);
            float t1 = sqg(p[(size_t)(base + 16 + l) * STRIDE]);
            float t2 = sqg(p[(size_t)(base + 32 + l) * STRIDE]);
            float t3 = sqg(p[(size_t)(base + 48 + l) * STRIDE]);
            float t4 = sqg(p[(size_t)(base + 64 + l) * STRIDE]);
            float t5 = sqg(p[(size_t)(base + 80 + l) * STRIDE]);
            float t6 = sqg(p[(size_t)(base + 96 + l) * STRIDE]);
            float t7 = sqg(p[(size_t)(base + 112 + l) * STRIDE]);
            c[l] = ((t0 + t1) + (t2 + t3)) + ((t4 + t5) + (t6 + t7));
        }
        float u[8];
#pragma unroll
        for (int l = 0; l < 8; ++l) u[l] = c[l] + c[l + 8];
        float v[4];
#pragma unroll
        for (int l = 0; l < 4; ++l) v[l] = u[l] + u[l + 4];
        float w0 = v[0] + v[2];
        float w1 = v[1] + v[3];
        float hh = w0 + w1;
        total = (h == 0) ? hh : (total + hh);
    }
    return total;
}

// Fused setup: blocks 0-3 = e2 + counts-zero + per-block emb-norm max (plain store);
// blocks 4-35 = bf16 E image prep.  ebf[p][c] = 16B = e[c][8p..8p+7] bf16.
__global__ __launch_bounds__(256) void k_setup(const float* __restrict__ emb,
                                               float* __restrict__ e2,
                                               float* __restrict__ emax4,
                                               int* __restrict__ counts,
                                               char* __restrict__ ebf) {
    const int bid = blockIdx.x;
    const int tid = threadIdx.x;
    if (bid < 4) {
        const int k = bid * 256 + tid;
        float v = np_sumsq256<1>(emb + (size_t)k * EMB_DIM);
        e2[k] = v;
        counts[k] = 0;
        __shared__ float red[256];
        red[tid] = sqrtf(v);
        __syncthreads();
        for (int s = 128; s > 0; s >>= 1) {
            if (tid < s) red[tid] = fmaxf(red[tid], red[tid + s]);
            __syncthreads();
        }
        if (tid == 0) emax4[bid] = red[0];
    } else {
        const int t = (bid - 4) * 256 + tid;   // 8192 threads
        const int c = t & 1023;
        const int s = t >> 10;                 // 0..7
#pragma unroll
        for (int g = 0; g < 4; ++g) {
            const int p = s + 8 * g;
            const float* e = emb + (size_t)c * EMB_DIM + 8 * p;
            unsigned h[8];
#pragma unroll
            for (int j = 0; j < 8; ++j) h[j] = f2bf(e[j]);
            uint4 w;
            w.x = h[0] | (h[1] << 16);
            w.y = h[2] | (h[3] << 16);
            w.z = h[4] | (h[5] << 16);
            w.w = h[6] | (h[7] << 16);
            *(uint4*)(ebf + ((size_t)p << 14) + ((size_t)c << 4)) = w;
        }
    }
}

// Fused distance+argmin+quantize. 1024 blocks x 256 thr (4 waves), 4 blocks/CU
// (R15). R16: X staging loads vectorized to float2 along l — thread (o, h-half,
// row-pair) loads both rows' values in one 8B load; per-row numpy pairwise tree
// computed by one thread from its own loads, bit-identical to the scalar path.
__global__ __launch_bounds__(256, 4) void k_dist(
    const float* __restrict__ in, const char* __restrict__ ebf,
    const float* __restrict__ emb, const float* __restrict__ e2g,
    const float* __restrict__ emax4,
    int* __restrict__ idx, int* __restrict__ counts,
    float* __restrict__ qout, double* __restrict__ ssep,
    int2* __restrict__ rowListG)
{
    __shared__ __align__(16) char pool[32768];  // X tile; xlds|queue|rowBest; then T|rd
    __shared__ float e2s[1024];
    __shared__ float vpart[64][8];
    __shared__ float A_lds[64];
    __shared__ float wRow[64];
    __shared__ unsigned rowMinU[64];
    __shared__ int rowCnt[64];
    __shared__ int rrows[64];
    __shared__ int rslot[64];
    __shared__ int qn, nrr;

    const int tid = threadIdx.x;
    const int n0 = blockIdx.x << 6;
    const int b = n0 >> 11;
    const int l0 = n0 & 2047;
    const int lane = tid & 63;
    const int wv = tid >> 6;
    const int lm = lane & 31;
    const int lh = lane >> 5;
    int2* rlist = rowListG + ((size_t)blockIdx.x << 10);   // 64 rows x 16 slots

    if (tid < 64) { rowMinU[tid] = 0xFFFFFFFFu; rowCnt[tid] = 0; }
    if (tid == 0) { qn = 0; nrr = 0; }
    ((float4*)e2s)[tid] = ((const float4*)e2g)[tid];   // 1024 floats

    // ---- stage X (bf16, 16-slot XOR swizzle) + exact numpy-pairwise rowsum ----
    // float2 along l: thread (o, hh, rp) owns d-class o of 128-half hh for rows
    // 2rp, 2rp+1. Same squares, same per-row tree, same single-writer per (r,d).
    {
        const int o  = tid >> 6;          // d residue class (mod 4)
        const int hh = (tid >> 5) & 1;    // which 128-half of d
        const int rp = tid & 31;          // row pair: rows 2rp, 2rp+1
        const int r0 = 2 * rp;
        const int r1 = r0 + 1;
        const float* xcol = in + (size_t)b * 524288 + l0 + r0;
        float ta[32], tb[32];
#pragma unroll
        for (int it = 0; it < 32; ++it) {
            const int d = 128 * hh + 4 * it + o;
            const float2 v2 = *(const float2*)(xcol + (size_t)d * 2048);
            *(unsigned short*)(pool + r0 * 512 + ((2 * d) ^ ((r0 & 15) << 4))) = f2bf(v2.x);
            *(unsigned short*)(pool + r1 * 512 + ((2 * d) ^ ((r1 & 15) << 4))) = f2bf(v2.y);
            ta[it] = sqg(v2.x);
            tb[it] = sqg(v2.y);
        }
        float cja[4], cjb[4];
#pragma unroll
        for (int j = 0; j < 4; ++j) {
            cja[j] = ((ta[j] + ta[4 + j]) + (ta[8 + j] + ta[12 + j]))
                   + ((ta[16 + j] + ta[20 + j]) + (ta[24 + j] + ta[28 + j]));
            cjb[j] = ((tb[j] + tb[4 + j]) + (tb[8 + j] + tb[12 + j]))
                   + ((tb[16 + j] + tb[20 + j]) + (tb[24 + j] + tb[28 + j]));
        }
        vpart[r0][hh * 4 + o] = (cja[0] + cja[2]) + (cja[1] + cja[3]);
        vpart[r1][hh * 4 + o] = (cjb[0] + cjb[2]) + (cjb[1] + cjb[3]);
    }
    __syncthreads();
    const float EMX = fmaxf(fmaxf(emax4[0], emax4[1]), fmaxf(emax4[2], emax4[3]));
    if (tid < 64) {
        const float* vp = vpart[tid];
        float h0 = (vp[0] + vp[2]) + (vp[1] + vp[3]);
        float h1 = (vp[4] + vp[6]) + (vp[5] + vp[7]);
        float A = h0 + h1;
        A_lds[tid] = A;
        // rigorous: 2*E_mfma + rounding slop = 2^-7 * ||x|| * max||e|| + 1e-4
        wRow[tid] = 0.0078125f * sqrtf(A) * EMX + 1.0e-4f;
    }
    __syncthreads();

    const int rsw = (lm & 15) << 4;     // same for rows lm and lm+32
    const int rb0 = lm * 512;
    const int rb1 = (32 + lm) * 512;
    const float wr0 = wRow[lm];
    const float wr1 = wRow[32 + lm];

    for (int pass = 0; pass < 4; ++pass) {
        const int cbase = pass * 256 + wv * 64;
        const int c0 = cbase + lm;      // eA input codes (A-frag row = lane&31)
        const int c1 = c0 + 32;         // eB

        f32x16 acc00, acc01, acc10, acc11;   // [e-frag][x-frag]
#pragma unroll
        for (int i = 0; i < 16; ++i) { acc00[i] = 0.f; acc01[i] = 0.f; acc10[i] = 0.f; acc11[i] = 0.f; }

        // 1-deep pipeline (4-deep measured null in R10; keep simplest form)
        const char* bp0 = ebf + ((size_t)lh << 14);
        short8v eAc = *(const short8v*)(bp0 + ((size_t)c0 << 4));
        short8v eBc = *(const short8v*)(bp0 + ((size_t)c1 << 4));
        for (int ks = 0; ks < 16; ++ks) {
            short8v eAn, eBn;
            if (ks < 15) {
                const char* bp = ebf + ((size_t)(2 * ks + 2 + lh) << 14);
                eAn = *(const short8v*)(bp + ((size_t)c0 << 4));
                eBn = *(const short8v*)(bp + ((size_t)c1 << 4));
            }
            const int koff = 32 * ks + 16 * lh;
            short8v x0 = *(const short8v*)(pool + rb0 + (koff ^ rsw));
            short8v x1 = *(const short8v*)(pool + rb1 + (koff ^ rsw));
            acc00 = MFMA(eAc, x0, acc00);
            acc01 = MFMA(eAc, x1, acc01);
            acc10 = MFMA(eBc, x0, acc10);
            acc11 = MFMA(eBc, x1, acc11);
            if (ks < 15) { eAc = eAn; eBc = eBn; }
        }

        // scores in place: s = e2[code] - 2*dot; per-row min purely in-register
        float rm0 = FLT_MAX, rm1 = FLT_MAX;
#pragma unroll
        for (int i = 0; i < 16; ++i) {
            const int crow = (i & 3) + 8 * (i >> 2) + 4 * lh;
            const float ezA = e2s[cbase + crow];
            const float ezB = e2s[cbase + 32 + crow];
            acc00[i] = __builtin_fmaf(-2.f, acc00[i], ezA);
            acc10[i] = __builtin_fmaf(-2.f, acc10[i], ezB);
            acc01[i] = __builtin_fmaf(-2.f, acc01[i], ezA);
            acc11[i] = __builtin_fmaf(-2.f, acc11[i], ezB);
            rm0 = fminf(rm0, fminf(acc00[i], acc10[i]));
            rm1 = fminf(rm1, fminf(acc01[i], acc11[i]));
        }
        atomicMin(&rowMinU[lm], f2ord(rm0));
        atomicMin(&rowMinU[32 + lm], f2ord(rm1));
        __syncthreads();   // tight thresholds: all waves' minima for passes <= pass

        const float thr0 = ord2f(rowMinU[lm]) + wr0;
        const float thr1 = ord2f(rowMinU[32 + lm]) + wr1;
#pragma unroll
        for (int i = 0; i < 16; ++i) {
            const int crow = (i & 3) + 8 * (i >> 2) + 4 * lh;
            const int ccA = cbase + crow;
            const int ccB = ccA + 32;
            if (acc00[i] <= thr0) { int p = atomicAdd(&rowCnt[lm], 1);      if (p < 16) rlist[lm * 16 + p]        = make_int2(ccA, __float_as_int(acc00[i])); }
            if (acc10[i] <= thr0) { int p = atomicAdd(&rowCnt[lm], 1);      if (p < 16) rlist[lm * 16 + p]        = make_int2(ccB, __float_as_int(acc10[i])); }
            if (acc01[i] <= thr1) { int p = atomicAdd(&rowCnt[32 + lm], 1); if (p < 16) rlist[(32 + lm) * 16 + p] = make_int2(ccA, __float_as_int(acc01[i])); }
            if (acc11[i] <= thr1) { int p = atomicAdd(&rowCnt[32 + lm], 1); if (p < 16) rlist[(32 + lm) * 16 + p] = make_int2(ccB, __float_as_int(acc11[i])); }
        }
    }
    __syncthreads();

    // ---- X tile dead: overlay xlds (16 rows fp32) | queue | rowBest in pool ----
    float* xlds = (float*)pool;                                        // 16 KB
    int2* queue = (int2*)(pool + 16384);                               // 8 KB (max 1024)
    unsigned long long* rowBest = (unsigned long long*)(pool + 24576); // 512 B

    int myBest = -1;
    if (tid < 64) {
        const int rr = tid;
        const int myCnt = rowCnt[rr];
        rowBest[rr] = ~0ull;
        rslot[rr] = -1;
        bool need = false;
        if (myCnt > 16) {
            need = true;   // overflow: exact full scan from LDS rows below
        } else {
            const float thr = ord2f(rowMinU[rr]) + wRow[rr];
            int myNv = 0, lk = -1;
            for (int s = 0; s < myCnt; ++s) {
                int2 en = rlist[rr * 16 + s];
                if (__int_as_float(en.y) <= thr) { ++myNv; lk = en.x; }
            }
            if (myNv == 1) {
                myBest = lk;
            } else {
                need = true;
                for (int s = 0; s < myCnt; ++s) {
                    int2 en = rlist[rr * 16 + s];
                    if (__int_as_float(en.y) <= thr) {
                        int p = atomicAdd(&qn, 1);
                        queue[p] = make_int2(rr, en.x);
                    }
                }
            }
        }
        if (need) { int s = atomicAdd(&nrr, 1); rrows[s] = rr; rslot[rr] = s; }
    }
    __syncthreads();

    const int QN = qn;
    const int NR = nrr;
    for (int chunk = 0; chunk < NR; chunk += 16) {
        const int cn = (NR - chunk < 16) ? (NR - chunk) : 16;
        // cooperative fp32 row copy (bit-exact; L2-hot from staging)
        for (int i = tid; i < cn * 256; i += 256) {
            const int s = i >> 8;
            const int d = i & 255;
            const int rr = rrows[chunk + s];
            xlds[s * 256 + d] = in[(size_t)b * 524288 + (size_t)d * 2048 + (l0 + rr)];
        }
        __syncthreads();
        // queue rescore for rows in this chunk: exact ascending-d fmaf chain, x from LDS
        for (int e = tid; e < QN; e += 256) {
            const int2 en = queue[e];
            const int rr = en.x;
            const int sl = rslot[rr] - chunk;
            if (sl < 0 || sl >= cn) continue;
            const int k = en.y;
            const float* xr = xlds + sl * 256;
            const float* er = emb + (size_t)k * EMB_DIM;
            float acc2 = 0.0f;
            for (int d = 0; d < 256; d += 4) {
                const float4 ev = *(const float4*)(er + d);
                const float4 xv = *(const float4*)(xr + d);
                acc2 = __builtin_fmaf(xv.x, ev.x, acc2);
                acc2 = __builtin_fmaf(xv.y, ev.y, acc2);
                acc2 = __builtin_fmaf(xv.z, ev.z, acc2);
                acc2 = __builtin_fmaf(xv.w, ev.w, acc2);
            }
            const float t = A_lds[rr] + e2s[k];
            const float dist = t - 2.0f * acc2;
            const unsigned long long pk = ((unsigned long long)f2ord(dist) << 32) | (unsigned)k;
            atomicMin(&rowBest[rr], pk);
        }
        // overflow rows in this chunk: all 1024 codes, 4 per thread, x from LDS
        for (int i = tid; i < cn * 256; i += 256) {
            const int s = i >> 8;
            const int rr = rrows[chunk + s];
            if (rowCnt[rr] <= 16) continue;
            const int kb = i & 255;
            const float* xr = xlds + s * 256;
            const float A = A_lds[rr];
            for (int k = kb; k < NUM_EMB; k += 256) {
                const float* er = emb + (size_t)k * EMB_DIM;
                float acc2 = 0.0f;
                for (int d = 0; d < 256; d += 4) {
                    const float4 ev = *(const float4*)(er + d);
                    const float4 xv = *(const float4*)(xr + d);
                    acc2 = __builtin_fmaf(xv.x, ev.x, acc2);
                    acc2 = __builtin_fmaf(xv.y, ev.y, acc2);
                    acc2 = __builtin_fmaf(xv.z, ev.z, acc2);
                    acc2 = __builtin_fmaf(xv.w, ev.w, acc2);
                }
                const float t = A + e2s[k];
                const float dist = t - 2.0f * acc2;
                const unsigned long long pk = ((unsigned long long)f2ord(dist) << 32) | (unsigned)k;
                atomicMin(&rowBest[rr], pk);
            }
        }
        __syncthreads();   // protect xlds before next chunk's copy
    }

    if (tid < 64) {
        int bk = myBest;
        if (bk < 0) bk = (int)(rowBest[tid] & 0xFFFFFFFFull);
        idx[n0 + tid] = bk;
        atomicAdd(&counts[bk], 1);
        rowCnt[tid] = bk;   // reuse as on-chip lidx for the quant tail
    }
    __syncthreads();

    // ---- fused quantize tail (was k_quant): rows (b, l0..l0+63), all 256 c ----
    // pool is dead again: T[64][65] fp32 (16.6 KB) + rd double[256] (2 KB).
    float* T = (float*)pool;
    double* rd = (double*)(pool + 20480);
    double sse = 0.0;
    for (int ch = 0; ch < 4; ++ch) {
        // load: T[lo][cl] = emb[lidx[lo]][ch*64+cl]; lanes vary cl -> coalesced 256B
        for (int g = 0; g < 16; ++g) {
            const int lo = g * 4 + (tid >> 6);
            const int cl = tid & 63;
            T[lo * 65 + cl] = emb[(size_t)rowCnt[lo] * EMB_DIM + ch * 64 + cl];
        }
        __syncthreads();
        // write + SSE: lanes vary lo -> coalesced 256B stores; T read stride 65 (conflict-free)
        for (int g = 0; g < 16; ++g) {
            const int cl = g * 4 + (tid >> 6);
            const int lo = tid & 63;
            const float q = T[lo * 65 + cl];
            const size_t ga = (size_t)b * 524288 + (size_t)(ch * 64 + cl) * 2048 + l0 + lo;
            const float x = in[ga];
            qout[ga] = q;
            const float d = q - x;
            sse += (double)d * (double)d;
        }
        __syncthreads();   // protect T before next chunk's load
    }
    rd[tid] = sse;
    __syncthreads();
    for (int st = 128; st > 0; st >>= 1) {
        if (tid < st) rd[tid] += rd[tid + st];
        __syncthreads();
    }
    if (tid == 0) ssep[blockIdx.x] = rd[0];
}

// one-hot encodings (float4 stores, every element rewritten every call) with the
// final loss/perplexity reduction folded into the last block: all of its inputs
// (ssep, counts) are complete before this kernel launches, so the designated
// block's reduction runs concurrently with the 256MB write wall.
__global__ __launch_bounds__(256) void k_enc(const int* __restrict__ idx,
                                             float* __restrict__ enc,
                                             const double* __restrict__ ssep,
                                             const int* __restrict__ counts,
                                             float* __restrict__ out)
{
    const int gid = blockIdx.x * 256 + threadIdx.x;   // 16777216 threads
    const int n = gid >> 8;
    const int kk = (gid & 255) << 2;
    const int e = idx[n];
    float4 v;
    v.x = (e == kk) ? 1.0f : 0.0f;
    v.y = (e == kk + 1) ? 1.0f : 0.0f;
    v.z = (e == kk + 2) ? 1.0f : 0.0f;
    v.w = (e == kk + 3) ? 1.0f : 0.0f;
    *(float4*)(enc + (size_t)n * NUM_EMB + kk) = v;

    if (blockIdx.x == 65535) {
        __shared__ double rd[256];
        const int tid = threadIdx.x;
        double s = 0.0;
        for (int i = tid; i < 1024; i += 256) s += ssep[i];
        rd[tid] = s;
        __syncthreads();
        for (int st = 128; st > 0; st >>= 1) {
            if (tid < st) rd[tid] += rd[tid + st];
            __syncthreads();
        }
        const double total = rd[0];
        __syncthreads();
        double pl = 0.0;
        for (int k = tid; k < 1024; k += 256) {
            const double p = (double)counts[k] * (1.0 / 65536.0);
            pl += p * log(p + 1e-10);
        }
        rd[tid] = pl;
        __syncthreads();
        for (int st = 128; st > 0; st >>= 1) {
            if (tid < st) rd[tid] += rd[tid + st];
            __syncthreads();
        }
        if (tid == 0) {
            out[0] = (float)(1.25 * (total * (1.0 / 16777216.0)));
            out[PERP_OFF] = (float)exp(-rd[0]);
        }
    }
}

extern "C" void kernel_launch(void* const* d_in, const int* in_sizes, int n_in,
                              void* d_out, int out_size, void* d_ws, size_t ws_size,
                              hipStream_t stream)
{
    const float* in  = (const float*)d_in[0];
    const float* emb = (const float*)d_in[1];
    float* out = (float*)d_out;
    char* ws = (char*)d_ws;
    int*     idx    = (int*)(ws + WS_IDX);
    float*   e2     = (float*)(ws + WS_E2);
    int*     counts = (int*)(ws + WS_COUNTS);
    double*  ssep   = (double*)(ws + WS_SSE);
    float*   emax4  = (float*)(ws + WS_EMX);

    // scratch carved from the encodings output region (overwritten later by k_enc):
    // [ebf: 512 KB bf16 E image][rowListG: 8 MB candidate lists]
    char* ebf = (char*)d_out + ((size_t)ENC_OFF * 4 + 8);
    int2* rowListG = (int2*)(ebf + (512 << 10));

    k_setup<<<dim3(36), dim3(256), 0, stream>>>(emb, e2, emax4, counts, ebf);
    k_dist<<<dim3(1024), dim3(256), 0, stream>>>(in, ebf, emb, e2, emax4, idx, counts,
                                                 out + Q_OFF, ssep, rowListG);
    k_enc<<<dim3(65536), dim3(256), 0, stream>>>(idx, out + ENC_OFF, ssep, counts, out);
}